// Round 2
// baseline (233.429 us; speedup 1.0000x reference)
//
#include <hip/hip_runtime.h>

// LIF neuron forward scan.
// currents: (T=64, B=256, D=2048) f32, beta_raw: (D,) f32
// out: [spikes (T,B,D) | final_mem (B,D)] f32
//
// One thread owns 4 consecutive d-lanes of one (b) row; iterates T serially.
// Memory-bound: ~270 MB total traffic, ~43 us floor at 6.3 TB/s.

#define T_STEPS 64
#define B_SZ 256
#define D_SZ 2048
#define BD (B_SZ * D_SZ)          // 524288
#define NVEC (BD / 4)             // 131072 float4 columns

__global__ __launch_bounds__(256) void lif_fwd_kernel(
    const float* __restrict__ currents,
    const float* __restrict__ beta_raw,
    float* __restrict__ out)
{
    const int idx = blockIdx.x * blockDim.x + threadIdx.x;  // [0, NVEC)
    const int d4  = idx & (D_SZ / 4 - 1);                    // float4 index within D

    // beta = sigmoid(beta_raw), computed in f64 then rounded to f32
    // (closest match to a correctly-rounded reference sigmoid).
    const float4 br = reinterpret_cast<const float4*>(beta_raw)[d4];
    const float b0 = (float)(1.0 / (1.0 + exp(-(double)br.x)));
    const float b1 = (float)(1.0 / (1.0 + exp(-(double)br.y)));
    const float b2 = (float)(1.0 / (1.0 + exp(-(double)br.z)));
    const float b3 = (float)(1.0 / (1.0 + exp(-(double)br.w)));

    const float4* __restrict__ cur = reinterpret_cast<const float4*>(currents) + idx;
    float4* __restrict__ spk       = reinterpret_cast<float4*>(out) + idx;

    float m0 = 0.f, m1 = 0.f, m2 = 0.f, m3 = 0.f;

    #pragma unroll 8
    for (int t = 0; t < T_STEPS; ++t) {
        const float4 c = cur[t * NVEC];
        // mem = beta*mem + cur  -- explicit rn mul+add, NO fma contraction,
        // to match numpy/XLA separate-op semantics bit-for-bit.
        m0 = __fadd_rn(__fmul_rn(b0, m0), c.x);
        m1 = __fadd_rn(__fmul_rn(b1, m1), c.y);
        m2 = __fadd_rn(__fmul_rn(b2, m2), c.z);
        m3 = __fadd_rn(__fmul_rn(b3, m3), c.w);

        const float s0 = (m0 >= 1.0f) ? 1.0f : 0.0f;
        const float s1 = (m1 >= 1.0f) ? 1.0f : 0.0f;
        const float s2 = (m2 >= 1.0f) ? 1.0f : 0.0f;
        const float s3 = (m3 >= 1.0f) ? 1.0f : 0.0f;

        spk[t * NVEC] = make_float4(s0, s1, s2, s3);

        // mem *= (1 - s): exactly 0 when s==1, unchanged when s==0 -> select.
        m0 = (s0 != 0.f) ? 0.f : m0;
        m1 = (s1 != 0.f) ? 0.f : m1;
        m2 = (s2 != 0.f) ? 0.f : m2;
        m3 = (s3 != 0.f) ? 0.f : m3;
    }

    // final_mem at offset T*B*D
    reinterpret_cast<float4*>(out + (size_t)T_STEPS * BD)[idx] =
        make_float4(m0, m1, m2, m3);
}

extern "C" void kernel_launch(void* const* d_in, const int* in_sizes, int n_in,
                              void* d_out, int out_size, void* d_ws, size_t ws_size,
                              hipStream_t stream)
{
    const float* currents = (const float*)d_in[0];
    const float* beta_raw = (const float*)d_in[1];
    float* out = (float*)d_out;

    const int threads = 256;
    const int blocks  = NVEC / threads;  // 512
    lif_fwd_kernel<<<blocks, threads, 0, stream>>>(currents, beta_raw, out);
}

// Round 4
// 230.179 us; speedup vs baseline: 1.0141x; 1.0141x over previous
//
#include <hip/hip_runtime.h>

// LIF neuron forward scan — R3: latency-hiding rewrite.
// currents: (T=64, B=256, D=2048) f32, beta_raw: (D,) f32
// out: [spikes (T,B,D) | final_mem (B,D)] f32
//
// R2 result: 233 us at only 1.16 TB/s -> latency-bound (2 waves/SIMD, shallow
// prefetch). Fix: float2/thread (4096 waves = 16/CU) + explicit depth-8
// register pipeline (fully unrolled T loop, static buffer indices) so each
// wave keeps 8 loads (4 KB) outstanding. Floor: 270 MB @ 6.3 TB/s ~ 43 us.

#define T_STEPS 64
#define B_SZ 256
#define D_SZ 2048
#define BD (B_SZ * D_SZ)          // 524288
#define NVEC2 (BD / 2)            // 262144 float2 columns
#define PF 8                      // prefetch depth (power of 2)

__global__ __launch_bounds__(256) void lif_fwd_kernel(
    const float* __restrict__ currents,
    const float* __restrict__ beta_raw,
    float* __restrict__ out)
{
    const int idx = blockIdx.x * blockDim.x + threadIdx.x;  // [0, NVEC2)
    const int d2  = idx & (D_SZ / 2 - 1);                   // float2 index within D

    // beta = sigmoid(beta_raw) in f64, rounded once to f32 (matches a
    // correctly-rounded reference sigmoid; same as passing R2 version).
    const float2 br = reinterpret_cast<const float2*>(beta_raw)[d2];
    const float b0 = (float)(1.0 / (1.0 + exp(-(double)br.x)));
    const float b1 = (float)(1.0 / (1.0 + exp(-(double)br.y)));

    const float2* __restrict__ cur = reinterpret_cast<const float2*>(currents) + idx;
    float2* __restrict__ spk       = reinterpret_cast<float2*>(out) + idx;

    float m0 = 0.f, m1 = 0.f;

    // Rotating register pipeline: issue PF loads up front, then per step
    // consume buf[t&(PF-1)] and immediately refill it with load t+PF.
    float2 buf[PF];
    #pragma unroll
    for (int k = 0; k < PF; ++k)
        buf[k] = cur[k * NVEC2];

    #pragma unroll
    for (int t = 0; t < T_STEPS; ++t) {
        const float2 c = buf[t & (PF - 1)];
        if (t + PF < T_STEPS)
            buf[t & (PF - 1)] = cur[(t + PF) * NVEC2];

        // mem = beta*mem + cur : explicit rn mul+add, NO fma contraction
        // (bit-match to numpy/XLA separate-op semantics).
        m0 = __fadd_rn(__fmul_rn(b0, m0), c.x);
        m1 = __fadd_rn(__fmul_rn(b1, m1), c.y);

        const float s0 = (m0 >= 1.0f) ? 1.0f : 0.0f;
        const float s1 = (m1 >= 1.0f) ? 1.0f : 0.0f;

        spk[t * NVEC2] = make_float2(s0, s1);

        // reset: mem*(1-s) is exactly 0 when s==1, unchanged when s==0.
        m0 = (s0 != 0.f) ? 0.f : m0;
        m1 = (s1 != 0.f) ? 0.f : m1;
    }

    // final_mem at offset T*B*D
    reinterpret_cast<float2*>(out + (size_t)T_STEPS * BD)[idx] =
        make_float2(m0, m1);
}

extern "C" void kernel_launch(void* const* d_in, const int* in_sizes, int n_in,
                              void* d_out, int out_size, void* d_ws, size_t ws_size,
                              hipStream_t stream)
{
    const float* currents = (const float*)d_in[0];
    const float* beta_raw = (const float*)d_in[1];
    float* out = (float*)d_out;

    const int threads = 256;
    const int blocks  = NVEC2 / threads;  // 1024
    lif_fwd_kernel<<<blocks, threads, 0, stream>>>(currents, beta_raw, out);
}

// Round 6
// 223.352 us; speedup vs baseline: 1.0451x; 1.0306x over previous
//
#include <hip/hip_runtime.h>

// LIF neuron forward scan — R6: float4(ext_vector) + PF=8 pipeline + nt hints.
// currents: (T=64, B=256, D=2048) f32, beta_raw: (D,) f32
// out: [spikes (T,B,D) | final_mem (B,D)] f32
//
// R5 failed compile: __builtin_nontemporal_* requires native vector types,
// not HIP_vector_type structs. Use ext_vector_type(4) float for all global
// accesses. Evidence (R2/R4): reported ~231 us is harness-poison dominated;
// our kernel is < 81 us. Kernel floor: 270 MB @ 6.3 TB/s ~ 43 us.

#define T_STEPS 64
#define B_SZ 256
#define D_SZ 2048
#define BD (B_SZ * D_SZ)          // 524288
#define NVEC (BD / 4)             // 131072 float4 columns
#define PF 8                      // prefetch depth (power of 2)

typedef float f32x4 __attribute__((ext_vector_type(4)));

__global__ __launch_bounds__(256) void lif_fwd_kernel(
    const float* __restrict__ currents,
    const float* __restrict__ beta_raw,
    float* __restrict__ out)
{
    const int idx = blockIdx.x * blockDim.x + threadIdx.x;  // [0, NVEC)
    const int d4  = idx & (D_SZ / 4 - 1);                   // float4 index within D

    // beta = sigmoid(beta_raw) in f64, rounded once to f32 (same as the
    // passing R2/R3 versions).
    const f32x4 br = reinterpret_cast<const f32x4*>(beta_raw)[d4];
    const float b0 = (float)(1.0 / (1.0 + exp(-(double)br.x)));
    const float b1 = (float)(1.0 / (1.0 + exp(-(double)br.y)));
    const float b2 = (float)(1.0 / (1.0 + exp(-(double)br.z)));
    const float b3 = (float)(1.0 / (1.0 + exp(-(double)br.w)));

    const f32x4* __restrict__ cur = reinterpret_cast<const f32x4*>(currents) + idx;
    f32x4* __restrict__ spk       = reinterpret_cast<f32x4*>(out) + idx;

    float m0 = 0.f, m1 = 0.f, m2 = 0.f, m3 = 0.f;

    // Rotating register pipeline, nontemporal (streaming) loads:
    // read-once data, don't pollute L2/L3.
    f32x4 buf[PF];
    #pragma unroll
    for (int k = 0; k < PF; ++k)
        buf[k] = __builtin_nontemporal_load(&cur[k * NVEC]);

    #pragma unroll
    for (int t = 0; t < T_STEPS; ++t) {
        const f32x4 c = buf[t & (PF - 1)];
        if (t + PF < T_STEPS)
            buf[t & (PF - 1)] = __builtin_nontemporal_load(&cur[(t + PF) * NVEC]);

        // mem = beta*mem + cur : explicit rn mul+add, NO fma contraction
        // (bit-match to numpy/XLA separate-op semantics).
        m0 = __fadd_rn(__fmul_rn(b0, m0), c.x);
        m1 = __fadd_rn(__fmul_rn(b1, m1), c.y);
        m2 = __fadd_rn(__fmul_rn(b2, m2), c.z);
        m3 = __fadd_rn(__fmul_rn(b3, m3), c.w);

        const float s0 = (m0 >= 1.0f) ? 1.0f : 0.0f;
        const float s1 = (m1 >= 1.0f) ? 1.0f : 0.0f;
        const float s2 = (m2 >= 1.0f) ? 1.0f : 0.0f;
        const float s3 = (m3 >= 1.0f) ? 1.0f : 0.0f;

        // write-once stream: nontemporal store.
        f32x4 sv; sv.x = s0; sv.y = s1; sv.z = s2; sv.w = s3;
        __builtin_nontemporal_store(sv, &spk[t * NVEC]);

        // reset: exactly 0 when s==1, unchanged when s==0.
        m0 = (s0 != 0.f) ? 0.f : m0;
        m1 = (s1 != 0.f) ? 0.f : m1;
        m2 = (s2 != 0.f) ? 0.f : m2;
        m3 = (s3 != 0.f) ? 0.f : m3;
    }

    // final_mem at offset T*B*D
    f32x4 mv; mv.x = m0; mv.y = m1; mv.z = m2; mv.w = m3;
    __builtin_nontemporal_store(mv,
        &reinterpret_cast<f32x4*>(out + (size_t)T_STEPS * BD)[idx]);
}

extern "C" void kernel_launch(void* const* d_in, const int* in_sizes, int n_in,
                              void* d_out, int out_size, void* d_ws, size_t ws_size,
                              hipStream_t stream)
{
    const float* currents = (const float*)d_in[0];
    const float* beta_raw = (const float*)d_in[1];
    float* out = (float*)d_out;

    const int threads = 256;
    const int blocks  = NVEC / threads;  // 512
    lif_fwd_kernel<<<blocks, threads, 0, stream>>>(currents, beta_raw, out);
}

// Round 8
// 222.111 us; speedup vs baseline: 1.0510x; 1.0056x over previous
//
#include <hip/hip_runtime.h>

// LIF neuron forward scan — R7: PF 8 -> 16 (32 MB in flight device-wide).
// currents: (T=64, B=256, D=2048) f32, beta_raw: (D,) f32
// out: [spikes (T,B,D) | final_mem (B,D)] f32
//
// Evidence: R3 (float2,PF8) ~= R6 (float4,PF8,nt) => in-flight bytes is the
// controlling variable (16 MB, ~3x BDP). Double prefetch depth to 32 MB.
// Reported dur_us is kernel + ~160 us harness reset; kernel est. 60-65 us,
// traffic floor 43 us (270 MB @ 6.3 TB/s).

#define T_STEPS 64
#define B_SZ 256
#define D_SZ 2048
#define BD (B_SZ * D_SZ)          // 524288
#define NVEC (BD / 4)             // 131072 float4 columns
#define PF 16                     // prefetch depth (power of 2)

typedef float f32x4 __attribute__((ext_vector_type(4)));

__global__ __launch_bounds__(256) void lif_fwd_kernel(
    const float* __restrict__ currents,
    const float* __restrict__ beta_raw,
    float* __restrict__ out)
{
    const int idx = blockIdx.x * blockDim.x + threadIdx.x;  // [0, NVEC)
    const int d4  = idx & (D_SZ / 4 - 1);                   // float4 index within D

    // beta = sigmoid(beta_raw) in f64, rounded once to f32 (same as all
    // passing rounds).
    const f32x4 br = reinterpret_cast<const f32x4*>(beta_raw)[d4];
    const float b0 = (float)(1.0 / (1.0 + exp(-(double)br.x)));
    const float b1 = (float)(1.0 / (1.0 + exp(-(double)br.y)));
    const float b2 = (float)(1.0 / (1.0 + exp(-(double)br.z)));
    const float b3 = (float)(1.0 / (1.0 + exp(-(double)br.w)));

    const f32x4* __restrict__ cur = reinterpret_cast<const f32x4*>(currents) + idx;
    f32x4* __restrict__ spk       = reinterpret_cast<f32x4*>(out) + idx;

    float m0 = 0.f, m1 = 0.f, m2 = 0.f, m3 = 0.f;

    // Rotating register pipeline, nontemporal streaming loads.
    f32x4 buf[PF];
    #pragma unroll
    for (int k = 0; k < PF; ++k)
        buf[k] = __builtin_nontemporal_load(&cur[k * NVEC]);

    #pragma unroll
    for (int t = 0; t < T_STEPS; ++t) {
        const f32x4 c = buf[t & (PF - 1)];
        if (t + PF < T_STEPS)
            buf[t & (PF - 1)] = __builtin_nontemporal_load(&cur[(t + PF) * NVEC]);

        // mem = beta*mem + cur : explicit rn mul+add, NO fma contraction
        // (bit-match to numpy/XLA separate-op semantics).
        m0 = __fadd_rn(__fmul_rn(b0, m0), c.x);
        m1 = __fadd_rn(__fmul_rn(b1, m1), c.y);
        m2 = __fadd_rn(__fmul_rn(b2, m2), c.z);
        m3 = __fadd_rn(__fmul_rn(b3, m3), c.w);

        const float s0 = (m0 >= 1.0f) ? 1.0f : 0.0f;
        const float s1 = (m1 >= 1.0f) ? 1.0f : 0.0f;
        const float s2 = (m2 >= 1.0f) ? 1.0f : 0.0f;
        const float s3 = (m3 >= 1.0f) ? 1.0f : 0.0f;

        // write-once stream: nontemporal store.
        f32x4 sv; sv.x = s0; sv.y = s1; sv.z = s2; sv.w = s3;
        __builtin_nontemporal_store(sv, &spk[t * NVEC]);

        // reset: exactly 0 when s==1, unchanged when s==0.
        m0 = (s0 != 0.f) ? 0.f : m0;
        m1 = (s1 != 0.f) ? 0.f : m1;
        m2 = (s2 != 0.f) ? 0.f : m2;
        m3 = (s3 != 0.f) ? 0.f : m3;
    }

    // final_mem at offset T*B*D
    f32x4 mv; mv.x = m0; mv.y = m1; mv.z = m2; mv.w = m3;
    __builtin_nontemporal_store(mv,
        &reinterpret_cast<f32x4*>(out + (size_t)T_STEPS * BD)[idx]);
}

extern "C" void kernel_launch(void* const* d_in, const int* in_sizes, int n_in,
                              void* d_out, int out_size, void* d_ws, size_t ws_size,
                              hipStream_t stream)
{
    const float* currents = (const float*)d_in[0];
    const float* beta_raw = (const float*)d_in[1];
    float* out = (float*)d_out;

    const int threads = 256;
    const int blocks  = NVEC / threads;  // 512
    lif_fwd_kernel<<<blocks, threads, 0, stream>>>(currents, beta_raw, out);
}